// Round 1
// baseline (428.191 us; speedup 1.0000x reference)
//
#include <hip/hip_runtime.h>
#include <math.h>

#define LL 5
#define HH 32
#define WW 128
#define CC 256
#define HEADS 8
#define DHH 32
#define HW (HH*WW)        // 4096
#define NTOK (LL*HW)      // 20480
#define LN_EPS 1e-5f

__device__ __forceinline__ int clamp01(int t) { return t < 0 ? 0 : (t > 1 ? 1 : t); }

// ---------------- LayerNorm: one wave per token row (C=256 = 64 lanes x float4)
__global__ __launch_bounds__(256) void ln_kernel(const float* __restrict__ x,
        const float* __restrict__ g, const float* __restrict__ b,
        float* __restrict__ xn) {
    int row = blockIdx.x * 4 + (threadIdx.x >> 6);
    int lane = threadIdx.x & 63;
    const float4 xv = *(const float4*)(x + (size_t)row * CC + lane * 4);
    float s1 = xv.x + xv.y + xv.z + xv.w;
    float s2 = xv.x * xv.x + xv.y * xv.y + xv.z * xv.z + xv.w * xv.w;
    #pragma unroll
    for (int off = 32; off; off >>= 1) {
        s1 += __shfl_xor(s1, off, 64);
        s2 += __shfl_xor(s2, off, 64);
    }
    float mu = s1 * (1.0f / CC);
    float inv = rsqrtf(s2 * (1.0f / CC) - mu * mu + LN_EPS);
    float4 gv = *(const float4*)(g + lane * 4);
    float4 bv = *(const float4*)(b + lane * 4);
    float4 o;
    o.x = (xv.x - mu) * inv * gv.x + bv.x;
    o.y = (xv.y - mu) * inv * gv.y + bv.y;
    o.z = (xv.z - mu) * inv * gv.z + bv.z;
    o.w = (xv.w - mu) * inv * gv.w + bv.w;
    *(float4*)(xn + (size_t)row * CC + lane * 4) = o;
}

// ---------------- Typed GEMM: out[n, j] = sum_k X[n,k] * W[type(l), j, k] + Bias[type(l), j]
// M = 4096 per l (grid.z = l), N = 256, K = 256.  64x64 tile, 4x4 per thread.
__global__ __launch_bounds__(256) void gemm_typed(const float* __restrict__ X,
        const float* __restrict__ W, const float* __restrict__ Bias,
        const float* __restrict__ prior, float* __restrict__ out) {
    __shared__ float Xs[32][68];
    __shared__ float Ws[32][68];
    int l = blockIdx.z;
    int t = clamp01((int)prior[(size_t)l * HW * 3 + 2]);
    const float* Wp = W + (size_t)t * 256 * 256;
    int m0 = l * HW + blockIdx.y * 64;
    int n0 = blockIdx.x * 64;
    int tx = threadIdx.x & 15, ty = threadIdx.x >> 4;
    int lrow = threadIdx.x >> 3;          // 0..31
    int lk = (threadIdx.x & 7) << 2;      // 0..28
    float acc[4][4] = {{0.f}};
    for (int kt = 0; kt < 256; kt += 32) {
        float4 x0 = *(const float4*)(X + (size_t)(m0 + lrow) * 256 + kt + lk);
        float4 x1 = *(const float4*)(X + (size_t)(m0 + lrow + 32) * 256 + kt + lk);
        float4 w0 = *(const float4*)(Wp + (size_t)(n0 + lrow) * 256 + kt + lk);
        float4 w1 = *(const float4*)(Wp + (size_t)(n0 + lrow + 32) * 256 + kt + lk);
        __syncthreads();
        Xs[lk + 0][lrow] = x0.x; Xs[lk + 1][lrow] = x0.y; Xs[lk + 2][lrow] = x0.z; Xs[lk + 3][lrow] = x0.w;
        Xs[lk + 0][lrow + 32] = x1.x; Xs[lk + 1][lrow + 32] = x1.y; Xs[lk + 2][lrow + 32] = x1.z; Xs[lk + 3][lrow + 32] = x1.w;
        Ws[lk + 0][lrow] = w0.x; Ws[lk + 1][lrow] = w0.y; Ws[lk + 2][lrow] = w0.z; Ws[lk + 3][lrow] = w0.w;
        Ws[lk + 0][lrow + 32] = w1.x; Ws[lk + 1][lrow + 32] = w1.y; Ws[lk + 2][lrow + 32] = w1.z; Ws[lk + 3][lrow + 32] = w1.w;
        __syncthreads();
        #pragma unroll
        for (int kk = 0; kk < 32; ++kk) {
            float4 av = *(const float4*)&Xs[kk][ty << 2];
            float4 bv = *(const float4*)&Ws[kk][tx << 2];
            float a[4] = {av.x, av.y, av.z, av.w};
            float bb[4] = {bv.x, bv.y, bv.z, bv.w};
            #pragma unroll
            for (int i = 0; i < 4; ++i)
                #pragma unroll
                for (int j = 0; j < 4; ++j) acc[i][j] += a[i] * bb[j];
        }
    }
    float4 bb4 = *(const float4*)(Bias + t * 256 + n0 + (tx << 2));
    #pragma unroll
    for (int i = 0; i < 4; ++i) {
        int row = m0 + (ty << 2) + i;
        float4 o;
        o.x = acc[i][0] + bb4.x; o.y = acc[i][1] + bb4.y;
        o.z = acc[i][2] + bb4.z; o.w = acc[i][3] + bb4.w;
        *(float4*)(out + (size_t)row * 256 + n0 + (tx << 2)) = o;
    }
}

// ---------------- Attention: grid (hw/8, heads). Block = 4 waves; each wave = 32 cols x 2 sites.
__global__ __launch_bounds__(256) void attn_kernel(
        const float* __restrict__ q, const float* __restrict__ k, const float* __restrict__ v,
        const int* __restrict__ mask, const float* __restrict__ prior,
        const float* __restrict__ relA, const float* __restrict__ relM,
        float* __restrict__ attout) {
    __shared__ float Wa[4096];
    __shared__ float Wm[4096];
    __shared__ float att_s[4][2][32];
    int m = blockIdx.y;
    for (int idx = threadIdx.x; idx < 4096; idx += 256) {
        int r = idx >> 10, pq = idx & 1023;
        Wa[idx] = relA[(size_t)(r * HEADS + m) * 1024 + pq];
        Wm[idx] = relM[(size_t)(r * HEADS + m) * 1024 + pq];
    }
    int t_[LL];
    #pragma unroll
    for (int i = 0; i < LL; ++i) t_[i] = clamp01((int)prior[(size_t)i * HW * 3 + 2]);
    __syncthreads();

    int wave = threadIdx.x >> 6, lane = threadIdx.x & 63;
    int col = lane & 31, half = lane >> 5;
    int hw = blockIdx.x * 8 + wave * 2 + half;

    float qr[LL], kr[LL], vr[LL];
    int msk[LL];
    #pragma unroll
    for (int j = 0; j < LL; ++j) {
        size_t n = (size_t)j * HW + hw;
        qr[j] = q[n * 256 + m * 32 + col];
        kr[j] = k[n * 256 + m * 32 + col];
        vr[j] = v[n * 256 + m * 32 + col];
        msk[j] = mask[hw * LL + j];
    }

    // qW[i][tj] = sum_p q[i][p] * W_att[t_i*2+tj][p][col]
    float qA[LL], qB[LL];
    #pragma unroll
    for (int i = 0; i < LL; ++i) {
        const float* wa0 = Wa + (t_[i] * 2 + 0) * 1024;
        const float* wa1 = Wa + (t_[i] * 2 + 1) * 1024;
        float a0 = 0.f, a1 = 0.f;
        #pragma unroll
        for (int p = 0; p < 32; ++p) {
            float qv = __shfl(qr[i], p, 32);
            a0 += qv * wa0[p * 32 + col];
            a1 += qv * wa1[p * 32 + col];
        }
        qA[i] = a0; qB[i] = a1;
    }

    const float scale = 0.17677669529663687f;  // 1/sqrt(32)
    #pragma unroll
    for (int i = 0; i < LL; ++i) {
        #pragma unroll
        for (int j = 0; j < LL; ++j) {
            float s = (t_[j] == 0 ? qA[i] : qB[i]) * kr[j];
            #pragma unroll
            for (int off = 16; off; off >>= 1) s += __shfl_xor(s, off, 32);
            s *= scale;
            if (msk[j] == 0) s = -1e9f;
            if (col == 0) att_s[wave][half][i * 5 + j] = s;
        }
    }

    // msg[j][ti] = sum_p v[j][p] * W_msg[ti*2+t_j][p][col]
    float m0r[LL], m1r[LL];
    #pragma unroll
    for (int j = 0; j < LL; ++j) {
        const float* w0 = Wm + (0 * 2 + t_[j]) * 1024;
        const float* w1 = Wm + (1 * 2 + t_[j]) * 1024;
        float a0 = 0.f, a1 = 0.f;
        #pragma unroll
        for (int p = 0; p < 32; ++p) {
            float vv = __shfl(vr[j], p, 32);
            a0 += vv * w0[p * 32 + col];
            a1 += vv * w1[p * 32 + col];
        }
        m0r[j] = a0; m1r[j] = a1;
    }
    __syncthreads();

    #pragma unroll
    for (int i = 0; i < LL; ++i) {
        float a[LL];
        #pragma unroll
        for (int j = 0; j < LL; ++j) a[j] = att_s[wave][half][i * 5 + j];
        float mx = fmaxf(fmaxf(fmaxf(a[0], a[1]), fmaxf(a[2], a[3])), a[4]);
        float e[LL], sum = 0.f;
        #pragma unroll
        for (int j = 0; j < LL; ++j) { e[j] = expf(a[j] - mx); sum += e[j]; }
        float inv = 1.f / sum;
        float o = 0.f;
        if (t_[i] == 0) {
            #pragma unroll
            for (int j = 0; j < LL; ++j) o += e[j] * inv * m0r[j];
        } else {
            #pragma unroll
            for (int j = 0; j < LL; ++j) o += e[j] * inv * m1r[j];
        }
        attout[((size_t)i * HW + hw) * 256 + m * 32 + col] = o;
    }
}

extern "C" void kernel_launch(void* const* d_in, const int* in_sizes, int n_in,
                              void* d_out, int out_size, void* d_ws, size_t ws_size,
                              hipStream_t stream) {
    (void)in_sizes; (void)n_in; (void)out_size; (void)ws_size;
    const float* x     = (const float*)d_in[0];
    const int*   mask  = (const int*)d_in[1];
    const float* prior = (const float*)d_in[2];
    const float* ln_g  = (const float*)d_in[3];
    const float* ln_b  = (const float*)d_in[4];
    const float* qw    = (const float*)d_in[5];
    const float* qb    = (const float*)d_in[6];
    const float* kw    = (const float*)d_in[7];
    const float* kb    = (const float*)d_in[8];
    const float* vw    = (const float*)d_in[9];
    const float* vb    = (const float*)d_in[10];
    const float* aw    = (const float*)d_in[11];
    const float* ab    = (const float*)d_in[12];
    const float* relA  = (const float*)d_in[13];
    const float* relM  = (const float*)d_in[14];
    float* out = (float*)d_out;

    float* ws = (float*)d_ws;
    const size_t BUF = (size_t)NTOK * 256;  // 5,242,880 floats
    float* xn = ws;
    float* q  = ws + BUF;
    float* k  = ws + 2 * BUF;
    float* v  = ws + 3 * BUF;
    float* attout = xn;  // reuse after QKV is done

    ln_kernel<<<NTOK / 4, 256, 0, stream>>>(x, ln_g, ln_b, xn);

    dim3 gg(4, 64, LL);
    gemm_typed<<<gg, 256, 0, stream>>>(xn, qw, qb, prior, q);
    gemm_typed<<<gg, 256, 0, stream>>>(xn, kw, kb, prior, k);
    gemm_typed<<<gg, 256, 0, stream>>>(xn, vw, vb, prior, v);

    attn_kernel<<<dim3(HW / 8, HEADS), 256, 0, stream>>>(q, k, v, mask, prior, relA, relM, attout);

    gemm_typed<<<gg, 256, 0, stream>>>(attout, aw, ab, prior, out);
}

// Round 2
// 166.379 us; speedup vs baseline: 2.5736x; 2.5736x over previous
//
#include <hip/hip_runtime.h>
#include <math.h>

#define LL 5
#define HH 32
#define WW 128
#define CC 256
#define HEADS 8
#define DHH 32
#define HW (HH*WW)        // 4096
#define NTOK (LL*HW)      // 20480
#define LN_EPS 1e-5f

typedef short bf16x8 __attribute__((ext_vector_type(8)));
typedef float f32x4 __attribute__((ext_vector_type(4)));

__device__ __forceinline__ int clamp01(int t) { return t < 0 ? 0 : (t > 1 ? 1 : t); }

__device__ __forceinline__ unsigned short f2b(float f) {
    union { float f; unsigned u; } v; v.f = f;
    unsigned r = v.u + 0x7FFFu + ((v.u >> 16) & 1u);  // RNE
    return (unsigned short)(r >> 16);
}
__device__ __forceinline__ float b2f(unsigned short u) {
    union { unsigned u; float f; } v; v.u = ((unsigned)u) << 16; return v.f;
}

// ---------------- LayerNorm -> bf16. One wave per token row.
__global__ __launch_bounds__(256) void ln_kernel(const float* __restrict__ x,
        const float* __restrict__ g, const float* __restrict__ b,
        unsigned short* __restrict__ xn) {
    int row = blockIdx.x * 4 + (threadIdx.x >> 6);
    int lane = threadIdx.x & 63;
    const float4 xv = *(const float4*)(x + (size_t)row * CC + lane * 4);
    float s1 = xv.x + xv.y + xv.z + xv.w;
    float s2 = xv.x * xv.x + xv.y * xv.y + xv.z * xv.z + xv.w * xv.w;
    #pragma unroll
    for (int off = 32; off; off >>= 1) {
        s1 += __shfl_xor(s1, off, 64);
        s2 += __shfl_xor(s2, off, 64);
    }
    float mu = s1 * (1.0f / CC);
    float inv = rsqrtf(s2 * (1.0f / CC) - mu * mu + LN_EPS);
    float4 gv = *(const float4*)(g + lane * 4);
    float4 bv = *(const float4*)(b + lane * 4);
    ushort4 o;
    o.x = f2b((xv.x - mu) * inv * gv.x + bv.x);
    o.y = f2b((xv.y - mu) * inv * gv.y + bv.y);
    o.z = f2b((xv.z - mu) * inv * gv.z + bv.z);
    o.w = f2b((xv.w - mu) * inv * gv.w + bv.w);
    *(ushort4*)(xn + (size_t)row * CC + lane * 4) = o;
}

// ---------------- fp32 -> bf16 weight conversion (qw and aw, 131072 elems each)
__global__ __launch_bounds__(256) void cvt_kernel(const float* __restrict__ qw,
        const float* __restrict__ aw,
        unsigned short* __restrict__ qwb, unsigned short* __restrict__ awb) {
    int i = blockIdx.x * 256 + threadIdx.x;
    qwb[i] = f2b(qw[i]);
    awb[i] = f2b(aw[i]);
}

// ---------------- Fold relation matrices into K/V projection weights.
// which=0: W'att[r][(m*32+p)][c] = sum_q Wa[r][m][p][q] * Wk[r&1][(m*32+q)][c]
// which=1: W'msg[r][(m*32+c')][c] = sum_p Wm[r][m][p][c'] * Wv[r&1][(m*32+p)][c]
// plus folded biases.
__global__ __launch_bounds__(256) void fold_kernel(
        const float* __restrict__ relA, const float* __restrict__ relM,
        const float* __restrict__ kw, const float* __restrict__ vw,
        const float* __restrict__ kb, const float* __restrict__ vb,
        unsigned short* __restrict__ wattb, unsigned short* __restrict__ wmsgb,
        float* __restrict__ batt, float* __restrict__ bmsg) {
    int blk = blockIdx.x;            // 0..63
    int r = blk & 3, m = (blk >> 2) & 7, which = blk >> 5;
    int tsel = r & 1;
    const float* S  = (which ? relM : relA) + ((size_t)r * 8 + m) * 1024;  // 32x32
    const float* Bg = (which ? vw : kw) + (size_t)tsel * 65536 + (size_t)m * 32 * 256;
    const float* bv = (which ? vb : kb) + tsel * 256 + m * 32;
    unsigned short* Wo = (which ? wmsgb : wattb) + ((size_t)r * 256 + m * 32) * 256;
    float* bo = (which ? bmsg : batt) + r * 256 + m * 32;

    __shared__ float Bl[32][256];
    for (int i = threadIdx.x; i < 32 * 256; i += 256)
        Bl[i >> 8][i & 255] = Bg[(size_t)(i >> 8) * 256 + (i & 255)];
    __syncthreads();

    int a  = threadIdx.x >> 3;        // 0..31 (output row)
    int c0 = (threadIdx.x & 7) * 4;   // column phase; c = c0 + cc*32 + e
    float srow[32];
    #pragma unroll
    for (int bq = 0; bq < 32; ++bq)
        srow[bq] = which ? S[bq * 32 + a] : S[a * 32 + bq];
    float acc[8][4] = {{0.f}};
    #pragma unroll
    for (int bq = 0; bq < 32; ++bq) {
        float s = srow[bq];
        #pragma unroll
        for (int cc = 0; cc < 8; ++cc) {
            float4 bb = *(const float4*)&Bl[bq][c0 + cc * 32];
            acc[cc][0] += s * bb.x; acc[cc][1] += s * bb.y;
            acc[cc][2] += s * bb.z; acc[cc][3] += s * bb.w;
        }
    }
    #pragma unroll
    for (int cc = 0; cc < 8; ++cc)
        #pragma unroll
        for (int e = 0; e < 4; ++e)
            Wo[a * 256 + c0 + cc * 32 + e] = f2b(acc[cc][e]);
    if (threadIdx.x < 32) {
        int p = threadIdx.x;
        float s = 0.f;
        #pragma unroll
        for (int bq = 0; bq < 32; ++bq)
            s += (which ? S[bq * 32 + p] : S[p * 32 + bq]) * bv[bq];
        bo[p] = s;
    }
}

// ---------------- bf16 MFMA GEMM: Out[n][j] = sum_k X[n][k]*W[sel][j][k] + Bias[sel][j]
// sel = idx_base + type(l(n)).  M tile 32 rows/block, 4 waves each own 64 cols.
template<bool OUT_BF16>
__global__ __launch_bounds__(256) void gemm_mfma(const short* __restrict__ X,
        const short* __restrict__ W, const float* __restrict__ Bias,
        const float* __restrict__ prior, int idx_base, void* __restrict__ Out) {
    int blkrow = blockIdx.x * 32;
    int l = blkrow >> 12;
    int t = clamp01((int)prior[(size_t)l * HW * 3 + 2]);
    int idx = idx_base + t;
    const short* Wp = W + (size_t)idx * 65536;
    const float* Bp = Bias + (size_t)idx * 256;

    int wave = threadIdx.x >> 6, lane = threadIdx.x & 63;
    int lr = lane & 15;              // A row / B col within 16
    int lk = (lane >> 4) * 8;        // k sub-offset

    f32x4 acc[2][4];
    #pragma unroll
    for (int mr = 0; mr < 2; ++mr)
        #pragma unroll
        for (int nr = 0; nr < 4; ++nr) acc[mr][nr] = (f32x4){0.f, 0.f, 0.f, 0.f};

    #pragma unroll
    for (int kk = 0; kk < 8; ++kk) {
        int k0 = kk * 32;
        bf16x8 af[2], bf[4];
        #pragma unroll
        for (int mr = 0; mr < 2; ++mr)
            af[mr] = *(const bf16x8*)(X + (size_t)(blkrow + mr * 16 + lr) * 256 + k0 + lk);
        #pragma unroll
        for (int nr = 0; nr < 4; ++nr)
            bf[nr] = *(const bf16x8*)(Wp + (size_t)(wave * 64 + nr * 16 + lr) * 256 + k0 + lk);
        #pragma unroll
        for (int mr = 0; mr < 2; ++mr)
            #pragma unroll
            for (int nr = 0; nr < 4; ++nr)
                acc[mr][nr] = __builtin_amdgcn_mfma_f32_16x16x32_bf16(af[mr], bf[nr], acc[mr][nr], 0, 0, 0);
    }

    #pragma unroll
    for (int nr = 0; nr < 4; ++nr) {
        int col = wave * 64 + nr * 16 + lr;
        float bias = Bp[col];
        #pragma unroll
        for (int mr = 0; mr < 2; ++mr) {
            #pragma unroll
            for (int rr = 0; rr < 4; ++rr) {
                int row = blkrow + mr * 16 + (lane >> 4) * 4 + rr;
                float val = acc[mr][nr][rr] + bias;
                if (OUT_BF16)
                    ((unsigned short*)Out)[(size_t)row * 256 + col] = f2b(val);
                else
                    ((float*)Out)[(size_t)row * 256 + col] = val;
            }
        }
    }
}

// ---------------- Final attention: 25 dot-32 + softmax + 25 FMA per (head, site)
__global__ __launch_bounds__(256) void attn_final(
        const unsigned short* __restrict__ Q, const unsigned short* __restrict__ Km,
        const unsigned short* __restrict__ Vm,
        const int* __restrict__ mask, const float* __restrict__ prior,
        unsigned short* __restrict__ outb) {
    const size_t TSTR = (size_t)NTOK * 256;
    int m = blockIdx.y;
    int wave = threadIdx.x >> 6, lane = threadIdx.x & 63;
    int col = lane & 31, half = lane >> 5;
    int hw = blockIdx.x * 8 + wave * 2 + half;

    int t_[LL], msk[LL];
    #pragma unroll
    for (int i = 0; i < LL; ++i) t_[i] = clamp01((int)prior[(size_t)i * HW * 3 + 2]);
    #pragma unroll
    for (int j = 0; j < LL; ++j) msk[j] = mask[hw * LL + j];

    float q[LL], km0[LL], km1[LL], vm0[LL], vm1[LL];
    #pragma unroll
    for (int j = 0; j < LL; ++j) {
        size_t idx = (size_t)(j * HW + hw) * 256 + m * 32 + col;
        q[j]   = b2f(Q[idx]);
        km0[j] = b2f(Km[idx]);
        km1[j] = b2f(Km[TSTR + idx]);
        vm0[j] = b2f(Vm[idx]);
        vm1[j] = b2f(Vm[TSTR + idx]);
    }

    const float scale = 0.17677669529663687f;  // 1/sqrt(32)
    #pragma unroll
    for (int i = 0; i < LL; ++i) {
        int sel = t_[i];
        float s[LL];
        #pragma unroll
        for (int j = 0; j < LL; ++j) {
            float pr = q[i] * (sel ? km1[j] : km0[j]);
            #pragma unroll
            for (int off = 16; off; off >>= 1) pr += __shfl_xor(pr, off);
            s[j] = msk[j] ? pr * scale : -1e9f;
        }
        float mx = fmaxf(fmaxf(fmaxf(s[0], s[1]), fmaxf(s[2], s[3])), s[4]);
        float e[LL], sum = 0.f;
        #pragma unroll
        for (int j = 0; j < LL; ++j) { e[j] = __expf(s[j] - mx); sum += e[j]; }
        float inv = 1.f / sum;
        float o = 0.f;
        #pragma unroll
        for (int j = 0; j < LL; ++j) o += e[j] * (sel ? vm1[j] : vm0[j]);
        o *= inv;
        outb[(size_t)(i * HW + hw) * 256 + m * 32 + col] = f2b(o);
    }
}

extern "C" void kernel_launch(void* const* d_in, const int* in_sizes, int n_in,
                              void* d_out, int out_size, void* d_ws, size_t ws_size,
                              hipStream_t stream) {
    (void)in_sizes; (void)n_in; (void)out_size; (void)ws_size;
    const float* x     = (const float*)d_in[0];
    const int*   mask  = (const int*)d_in[1];
    const float* prior = (const float*)d_in[2];
    const float* ln_g  = (const float*)d_in[3];
    const float* ln_b  = (const float*)d_in[4];
    const float* qw    = (const float*)d_in[5];
    const float* qb    = (const float*)d_in[6];
    const float* kw    = (const float*)d_in[7];
    const float* kb    = (const float*)d_in[8];
    const float* vw    = (const float*)d_in[9];
    const float* vb    = (const float*)d_in[10];
    const float* aw    = (const float*)d_in[11];
    const float* ab    = (const float*)d_in[12];
    const float* relA  = (const float*)d_in[13];
    const float* relM  = (const float*)d_in[14];
    float* out = (float*)d_out;

    // workspace layout (bytes); all tiles 256B-aligned
    char* ws = (char*)d_ws;
    const size_t TOKB = (size_t)NTOK * 256 * 2;  // 10,485,760 B (bf16 token buffer)
    unsigned short* xnb  = (unsigned short*)(ws);
    unsigned short* Qb   = (unsigned short*)(ws + TOKB);
    unsigned short* Kmb  = (unsigned short*)(ws + 2 * TOKB);  // 2 buffers
    unsigned short* Vmb  = (unsigned short*)(ws + 4 * TOKB);  // 2 buffers
    unsigned short* attb = (unsigned short*)(ws + 6 * TOKB);
    char* wsp = ws + 7 * TOKB;
    unsigned short* qwb   = (unsigned short*)(wsp);            wsp += 131072 * 2;
    unsigned short* awb   = (unsigned short*)(wsp);            wsp += 131072 * 2;
    unsigned short* wattb = (unsigned short*)(wsp);            wsp += 4 * 65536 * 2;
    unsigned short* wmsgb = (unsigned short*)(wsp);            wsp += 4 * 65536 * 2;
    float* batt = (float*)(wsp);                               wsp += 4 * 256 * 4;
    float* bmsg = (float*)(wsp);

    ln_kernel<<<NTOK / 4, 256, 0, stream>>>(x, ln_g, ln_b, xnb);
    cvt_kernel<<<131072 / 256, 256, 0, stream>>>(qw, aw, qwb, awb);
    fold_kernel<<<64, 256, 0, stream>>>(relA, relM, kw, vw, kb, vb, wattb, wmsgb, batt, bmsg);

    const int GB = NTOK / 32;  // 640 blocks
    gemm_mfma<true><<<GB, 256, 0, stream>>>((const short*)xnb, (const short*)qwb, qb, prior, 0, Qb);
    gemm_mfma<true><<<GB, 256, 0, stream>>>((const short*)xnb, (const short*)wattb, batt, prior, 0, Kmb);
    gemm_mfma<true><<<GB, 256, 0, stream>>>((const short*)xnb, (const short*)wattb, batt, prior, 2, Kmb + (size_t)NTOK * 256);
    gemm_mfma<true><<<GB, 256, 0, stream>>>((const short*)xnb, (const short*)wmsgb, bmsg, prior, 0, Vmb);
    gemm_mfma<true><<<GB, 256, 0, stream>>>((const short*)xnb, (const short*)wmsgb, bmsg, prior, 2, Vmb + (size_t)NTOK * 256);

    attn_final<<<dim3(HW / 8, HEADS), 256, 0, stream>>>(Qb, Kmb, Vmb, mask, prior, attb);

    gemm_mfma<false><<<GB, 256, 0, stream>>>((const short*)attb, (const short*)awb, ab, prior, 0, out);
}

// Round 4
// 121.374 us; speedup vs baseline: 3.5279x; 1.3708x over previous
//
#include <hip/hip_runtime.h>
#include <math.h>

#define LL 5
#define HH 32
#define WW 128
#define CC 256
#define HEADS 8
#define DHH 32
#define HW (HH*WW)        // 4096
#define NTOK (LL*HW)      // 20480
#define LN_EPS 1e-5f

typedef short bf16x8 __attribute__((ext_vector_type(8)));
typedef float f32x4 __attribute__((ext_vector_type(4)));

__device__ __forceinline__ int clamp01(int t) { return t < 0 ? 0 : (t > 1 ? 1 : t); }

__device__ __forceinline__ unsigned short f2b(float f) {
    union { float f; unsigned u; } v; v.f = f;
    unsigned r = v.u + 0x7FFFu + ((v.u >> 16) & 1u);  // RNE
    return (unsigned short)(r >> 16);
}
__device__ __forceinline__ float b2f(unsigned short u) {
    union { unsigned u; float f; } v; v.u = ((unsigned)u) << 16; return v.f;
}

// ---------------- Fused setup: LN (blocks 0..5119), cvt (5120..5631), fold (5632..5695)
__global__ __launch_bounds__(256) void setup_kernel(
        const float* __restrict__ x, const float* __restrict__ g, const float* __restrict__ b,
        unsigned short* __restrict__ xn,
        const float* __restrict__ qw, const float* __restrict__ aw,
        unsigned short* __restrict__ qwb, unsigned short* __restrict__ awb,
        const float* __restrict__ relA, const float* __restrict__ relM,
        const float* __restrict__ kw, const float* __restrict__ vw,
        const float* __restrict__ kb, const float* __restrict__ vb,
        unsigned short* __restrict__ wattb, unsigned short* __restrict__ wmsgb,
        float* __restrict__ batt, float* __restrict__ bmsg) {
    __shared__ float Bl[32][256];
    int blk = blockIdx.x;
    if (blk < 5120) {
        // ---- LayerNorm -> bf16, one wave per row
        int row = blk * 4 + (threadIdx.x >> 6);
        int lane = threadIdx.x & 63;
        const float4 xv = *(const float4*)(x + (size_t)row * CC + lane * 4);
        float s1 = xv.x + xv.y + xv.z + xv.w;
        float s2 = xv.x * xv.x + xv.y * xv.y + xv.z * xv.z + xv.w * xv.w;
        #pragma unroll
        for (int off = 32; off; off >>= 1) {
            s1 += __shfl_xor(s1, off, 64);
            s2 += __shfl_xor(s2, off, 64);
        }
        float mu = s1 * (1.0f / CC);
        float inv = rsqrtf(s2 * (1.0f / CC) - mu * mu + LN_EPS);
        float4 gv = *(const float4*)(g + lane * 4);
        float4 bv = *(const float4*)(b + lane * 4);
        ushort4 o;
        o.x = f2b((xv.x - mu) * inv * gv.x + bv.x);
        o.y = f2b((xv.y - mu) * inv * gv.y + bv.y);
        o.z = f2b((xv.z - mu) * inv * gv.z + bv.z);
        o.w = f2b((xv.w - mu) * inv * gv.w + bv.w);
        *(ushort4*)(xn + (size_t)row * CC + lane * 4) = o;
    } else if (blk < 5632) {
        int i = (blk - 5120) * 256 + threadIdx.x;
        qwb[i] = f2b(qw[i]);
        awb[i] = f2b(aw[i]);
    } else {
        // ---- fold relation matrices into K/V weights
        int fb = blk - 5632;          // 0..63
        int r = fb & 3, m = (fb >> 2) & 7, which = fb >> 5;
        int tsel = r & 1;
        const float* S  = (which ? relM : relA) + ((size_t)r * 8 + m) * 1024;
        const float* Bg = (which ? vw : kw) + (size_t)tsel * 65536 + (size_t)m * 32 * 256;
        const float* bv = (which ? vb : kb) + tsel * 256 + m * 32;
        unsigned short* Wo = (which ? wmsgb : wattb) + ((size_t)r * 256 + m * 32) * 256;
        float* bo = (which ? bmsg : batt) + r * 256 + m * 32;

        for (int i = threadIdx.x; i < 32 * 256; i += 256)
            Bl[i >> 8][i & 255] = Bg[(size_t)(i >> 8) * 256 + (i & 255)];
        __syncthreads();

        int a  = threadIdx.x >> 3;
        int c0 = (threadIdx.x & 7) * 4;
        float srow[32];
        #pragma unroll
        for (int bq = 0; bq < 32; ++bq)
            srow[bq] = which ? S[bq * 32 + a] : S[a * 32 + bq];
        float acc[8][4] = {{0.f}};
        #pragma unroll
        for (int bq = 0; bq < 32; ++bq) {
            float s = srow[bq];
            #pragma unroll
            for (int cc = 0; cc < 8; ++cc) {
                float4 bb = *(const float4*)&Bl[bq][c0 + cc * 32];
                acc[cc][0] += s * bb.x; acc[cc][1] += s * bb.y;
                acc[cc][2] += s * bb.z; acc[cc][3] += s * bb.w;
            }
        }
        #pragma unroll
        for (int cc = 0; cc < 8; ++cc)
            #pragma unroll
            for (int e = 0; e < 4; ++e)
                Wo[a * 256 + c0 + cc * 32 + e] = f2b(acc[cc][e]);
        if (threadIdx.x < 32) {
            int p = threadIdx.x;
            float s = 0.f;
            #pragma unroll
            for (int bq = 0; bq < 32; ++bq)
                s += (which ? S[bq * 32 + p] : S[p * 32 + bq]) * bv[bq];
            bo[p] = s;
        }
    }
}

// ---------------- Fused QKV-mod GEMM: grid (NTOK/64, 5). 64x256 tile, wave owns 64 cols.
// s=0: Q (qwb/qb), s=1,2: Km0/1 (wattb/batt), s=3,4: Vm0/1 (wmsgb/bmsg)
__global__ __launch_bounds__(256) void gemm_qkv(const short* __restrict__ X,
        const short* __restrict__ qwb, const short* __restrict__ wattb,
        const short* __restrict__ wmsgb,
        const float* __restrict__ qb, const float* __restrict__ batt,
        const float* __restrict__ bmsg,
        const float* __restrict__ prior, unsigned short* __restrict__ OutBase) {
    int blkrow = blockIdx.x * 64;
    int s = blockIdx.y;
    int l = blkrow >> 12;
    int t = clamp01((int)prior[(size_t)l * HW * 3 + 2]);

    const short* Wp; const float* Bp;
    if (s == 0)      { Wp = qwb   + (size_t)t * 65536;                 Bp = qb   + t * 256; }
    else if (s <= 2) { int i2 = (s - 1) * 2 + t; Wp = wattb + (size_t)i2 * 65536; Bp = batt + i2 * 256; }
    else             { int i2 = (s - 3) * 2 + t; Wp = wmsgb + (size_t)i2 * 65536; Bp = bmsg + i2 * 256; }
    unsigned short* Out = OutBase + (size_t)s * NTOK * 256;

    int wave = threadIdx.x >> 6, lane = threadIdx.x & 63;
    int lr = lane & 15, lk = (lane >> 4) * 8;

    f32x4 acc[4][4];
    #pragma unroll
    for (int mr = 0; mr < 4; ++mr)
        #pragma unroll
        for (int nr = 0; nr < 4; ++nr) acc[mr][nr] = (f32x4){0.f, 0.f, 0.f, 0.f};

    #pragma unroll
    for (int kk = 0; kk < 8; ++kk) {
        int k0 = kk * 32;
        bf16x8 af[4], bf[4];
        #pragma unroll
        for (int mr = 0; mr < 4; ++mr)
            af[mr] = *(const bf16x8*)(X + (size_t)(blkrow + mr * 16 + lr) * 256 + k0 + lk);
        #pragma unroll
        for (int nr = 0; nr < 4; ++nr)
            bf[nr] = *(const bf16x8*)(Wp + (size_t)(wave * 64 + nr * 16 + lr) * 256 + k0 + lk);
        #pragma unroll
        for (int mr = 0; mr < 4; ++mr)
            #pragma unroll
            for (int nr = 0; nr < 4; ++nr)
                acc[mr][nr] = __builtin_amdgcn_mfma_f32_16x16x32_bf16(af[mr], bf[nr], acc[mr][nr], 0, 0, 0);
    }

    #pragma unroll
    for (int nr = 0; nr < 4; ++nr) {
        int col = wave * 64 + nr * 16 + lr;
        float bias = Bp[col];
        #pragma unroll
        for (int mr = 0; mr < 4; ++mr) {
            #pragma unroll
            for (int rr = 0; rr < 4; ++rr) {
                int row = blkrow + mr * 16 + (lane >> 4) * 4 + rr;
                Out[(size_t)row * 256 + col] = f2b(acc[mr][nr][rr] + bias);
            }
        }
    }
}

// ---------------- Output GEMM: attb @ awb^T + ab -> fp32 out. 64x256 tile.
__global__ __launch_bounds__(256) void gemm_a(const short* __restrict__ X,
        const short* __restrict__ W, const float* __restrict__ Bias,
        const float* __restrict__ prior, float* __restrict__ Out) {
    int blkrow = blockIdx.x * 64;
    int l = blkrow >> 12;
    int t = clamp01((int)prior[(size_t)l * HW * 3 + 2]);
    const short* Wp = W + (size_t)t * 65536;
    const float* Bp = Bias + (size_t)t * 256;

    int wave = threadIdx.x >> 6, lane = threadIdx.x & 63;
    int lr = lane & 15, lk = (lane >> 4) * 8;

    f32x4 acc[4][4];
    #pragma unroll
    for (int mr = 0; mr < 4; ++mr)
        #pragma unroll
        for (int nr = 0; nr < 4; ++nr) acc[mr][nr] = (f32x4){0.f, 0.f, 0.f, 0.f};

    #pragma unroll
    for (int kk = 0; kk < 8; ++kk) {
        int k0 = kk * 32;
        bf16x8 af[4], bf[4];
        #pragma unroll
        for (int mr = 0; mr < 4; ++mr)
            af[mr] = *(const bf16x8*)(X + (size_t)(blkrow + mr * 16 + lr) * 256 + k0 + lk);
        #pragma unroll
        for (int nr = 0; nr < 4; ++nr)
            bf[nr] = *(const bf16x8*)(Wp + (size_t)(wave * 64 + nr * 16 + lr) * 256 + k0 + lk);
        #pragma unroll
        for (int mr = 0; mr < 4; ++mr)
            #pragma unroll
            for (int nr = 0; nr < 4; ++nr)
                acc[mr][nr] = __builtin_amdgcn_mfma_f32_16x16x32_bf16(af[mr], bf[nr], acc[mr][nr], 0, 0, 0);
    }

    #pragma unroll
    for (int nr = 0; nr < 4; ++nr) {
        int col = wave * 64 + nr * 16 + lr;
        float bias = Bp[col];
        #pragma unroll
        for (int mr = 0; mr < 4; ++mr) {
            #pragma unroll
            for (int rr = 0; rr < 4; ++rr) {
                int row = blkrow + mr * 16 + (lane >> 4) * 4 + rr;
                Out[(size_t)row * 256 + col] = acc[mr][nr][rr] + bias;
            }
        }
    }
}

// ---------------- Final attention: 25 dot-32 + softmax + 25 FMA per (head, site)
__global__ __launch_bounds__(256) void attn_final(
        const unsigned short* __restrict__ Q, const unsigned short* __restrict__ Km,
        const unsigned short* __restrict__ Vm,
        const int* __restrict__ mask, const float* __restrict__ prior,
        unsigned short* __restrict__ outb) {
    const size_t TSTR = (size_t)NTOK * 256;
    int m = blockIdx.y;
    int wave = threadIdx.x >> 6, lane = threadIdx.x & 63;
    int col = lane & 31, half = lane >> 5;
    int hw = blockIdx.x * 8 + wave * 2 + half;

    int t_[LL], msk[LL];
    #pragma unroll
    for (int i = 0; i < LL; ++i) t_[i] = clamp01((int)prior[(size_t)i * HW * 3 + 2]);
    #pragma unroll
    for (int j = 0; j < LL; ++j) msk[j] = mask[hw * LL + j];

    float q[LL], km0[LL], km1[LL], vm0[LL], vm1[LL];
    #pragma unroll
    for (int j = 0; j < LL; ++j) {
        size_t idx = (size_t)(j * HW + hw) * 256 + m * 32 + col;
        q[j]   = b2f(Q[idx]);
        km0[j] = b2f(Km[idx]);
        km1[j] = b2f(Km[TSTR + idx]);
        vm0[j] = b2f(Vm[idx]);
        vm1[j] = b2f(Vm[TSTR + idx]);
    }

    const float scale = 0.17677669529663687f;  // 1/sqrt(32)
    #pragma unroll
    for (int i = 0; i < LL; ++i) {
        int sel = t_[i];
        float s[LL];
        #pragma unroll
        for (int j = 0; j < LL; ++j) {
            float pr = q[i] * (sel ? km1[j] : km0[j]);
            #pragma unroll
            for (int off = 16; off; off >>= 1) pr += __shfl_xor(pr, off);
            s[j] = msk[j] ? pr * scale : -1e9f;
        }
        float mx = fmaxf(fmaxf(fmaxf(s[0], s[1]), fmaxf(s[2], s[3])), s[4]);
        float e[LL], sum = 0.f;
        #pragma unroll
        for (int j = 0; j < LL; ++j) { e[j] = __expf(s[j] - mx); sum += e[j]; }
        float inv = 1.f / sum;
        float o = 0.f;
        #pragma unroll
        for (int j = 0; j < LL; ++j) o += e[j] * (sel ? vm1[j] : vm0[j]);
        o *= inv;
        outb[(size_t)(i * HW + hw) * 256 + m * 32 + col] = f2b(o);
    }
}

extern "C" void kernel_launch(void* const* d_in, const int* in_sizes, int n_in,
                              void* d_out, int out_size, void* d_ws, size_t ws_size,
                              hipStream_t stream) {
    (void)in_sizes; (void)n_in; (void)out_size; (void)ws_size;
    const float* x     = (const float*)d_in[0];
    const int*   mask  = (const int*)d_in[1];
    const float* prior = (const float*)d_in[2];
    const float* ln_g  = (const float*)d_in[3];
    const float* ln_b  = (const float*)d_in[4];
    const float* qw    = (const float*)d_in[5];
    const float* qb    = (const float*)d_in[6];
    const float* kw    = (const float*)d_in[7];
    const float* kb    = (const float*)d_in[8];
    const float* vw    = (const float*)d_in[9];
    const float* vb    = (const float*)d_in[10];
    const float* aw    = (const float*)d_in[11];
    const float* ab    = (const float*)d_in[12];
    const float* relA  = (const float*)d_in[13];
    const float* relM  = (const float*)d_in[14];
    float* out = (float*)d_out;

    char* ws = (char*)d_ws;
    const size_t TOKB = (size_t)NTOK * 256 * 2;  // bf16 token buffer bytes
    unsigned short* xnb  = (unsigned short*)(ws);
    unsigned short* Qb   = (unsigned short*)(ws + TOKB);       // Q, Km0, Km1, Vm0, Vm1 contiguous
    unsigned short* Kmb  = (unsigned short*)(ws + 2 * TOKB);
    unsigned short* Vmb  = (unsigned short*)(ws + 4 * TOKB);
    unsigned short* attb = (unsigned short*)(ws + 6 * TOKB);
    char* wsp = ws + 7 * TOKB;
    unsigned short* qwb   = (unsigned short*)(wsp);            wsp += 131072 * 2;
    unsigned short* awb   = (unsigned short*)(wsp);            wsp += 131072 * 2;
    unsigned short* wattb = (unsigned short*)(wsp);            wsp += 4 * 65536 * 2;
    unsigned short* wmsgb = (unsigned short*)(wsp);            wsp += 4 * 65536 * 2;
    float* batt = (float*)(wsp);                               wsp += 4 * 256 * 4;
    float* bmsg = (float*)(wsp);

    setup_kernel<<<5696, 256, 0, stream>>>(x, ln_g, ln_b, xnb, qw, aw, qwb, awb,
                                           relA, relM, kw, vw, kb, vb,
                                           wattb, wmsgb, batt, bmsg);

    gemm_qkv<<<dim3(NTOK / 64, 5), 256, 0, stream>>>((const short*)xnb,
            (const short*)qwb, (const short*)wattb, (const short*)wmsgb,
            qb, batt, bmsg, prior, Qb);

    attn_final<<<dim3(HW / 8, HEADS), 256, 0, stream>>>(Qb, Kmb, Vmb, mask, prior, attb);

    gemm_a<<<NTOK / 64, 256, 0, stream>>>((const short*)attb, (const short*)awb, ab, prior, out);
}

// Round 5
// 83.868 us; speedup vs baseline: 5.1055x; 1.4472x over previous
//
#include <hip/hip_runtime.h>
#include <math.h>

#define LL 5
#define HH 32
#define WW 128
#define CC 256
#define HEADS 8
#define DHH 32
#define HW (HH*WW)        // 4096
#define NTOK (LL*HW)      // 20480
#define LN_EPS 1e-5f

typedef short bf16x8 __attribute__((ext_vector_type(8)));
typedef float f32x4 __attribute__((ext_vector_type(4)));
typedef unsigned short u16x8 __attribute__((ext_vector_type(8)));

__device__ __forceinline__ int clamp01(int t) { return t < 0 ? 0 : (t > 1 ? 1 : t); }

__device__ __forceinline__ unsigned short f2b(float f) {
    union { float f; unsigned u; } v; v.f = f;
    unsigned r = v.u + 0x7FFFu + ((v.u >> 16) & 1u);  // RNE
    return (unsigned short)(r >> 16);
}
__device__ __forceinline__ float b2f(unsigned short u) {
    union { unsigned u; float f; } v; v.u = ((unsigned)u) << 16; return v.f;
}

// Fragment-order offset (elements) for a row-major [R][256] matrix:
// frag[panel=row/16][kk=col/32][lane=(col%32)/8*16 + row%16][e=col%8]
__device__ __forceinline__ size_t frag_off(int row, int col) {
    return ((size_t)((row >> 4) * 8 + (col >> 5)) << 9)
         + (((col & 31) >> 3) << 7) + ((row & 15) << 3) + (col & 7);
}

// ---------------- Fused setup: LN (blocks 0..5119), cvt (5120..5247), fold (5248..5311)
__global__ __launch_bounds__(256) void setup_kernel(
        const float* __restrict__ x, const float* __restrict__ g, const float* __restrict__ b,
        unsigned short* __restrict__ xn,
        const float* __restrict__ qw, const float* __restrict__ aw,
        unsigned short* __restrict__ qwb, unsigned short* __restrict__ awb,
        const float* __restrict__ relA, const float* __restrict__ relM,
        const float* __restrict__ kw, const float* __restrict__ vw,
        const float* __restrict__ kb, const float* __restrict__ vb,
        unsigned short* __restrict__ wattb, unsigned short* __restrict__ wmsgb,
        float* __restrict__ batt, float* __restrict__ bmsg) {
    __shared__ float Bl[32][256];
    int blk = blockIdx.x;
    int wave = threadIdx.x >> 6, lane = threadIdx.x & 63;
    if (blk < 5120) {
        // ---- LayerNorm -> bf16 (fragment-order output), one wave per row
        int row = blk * 4 + wave;
        const float4 xv = *(const float4*)(x + (size_t)row * CC + lane * 4);
        float s1 = xv.x + xv.y + xv.z + xv.w;
        float s2 = xv.x * xv.x + xv.y * xv.y + xv.z * xv.z + xv.w * xv.w;
        #pragma unroll
        for (int off = 32; off; off >>= 1) {
            s1 += __shfl_xor(s1, off, 64);
            s2 += __shfl_xor(s2, off, 64);
        }
        float mu = s1 * (1.0f / CC);
        float inv = rsqrtf(s2 * (1.0f / CC) - mu * mu + LN_EPS);
        float4 gv = *(const float4*)(g + lane * 4);
        float4 bv = *(const float4*)(b + lane * 4);
        ushort4 o;
        o.x = f2b((xv.x - mu) * inv * gv.x + bv.x);
        o.y = f2b((xv.y - mu) * inv * gv.y + bv.y);
        o.z = f2b((xv.z - mu) * inv * gv.z + bv.z);
        o.w = f2b((xv.w - mu) * inv * gv.w + bv.w);
        *(ushort4*)(xn + frag_off(row, lane << 2)) = o;
    } else if (blk < 5248) {
        // ---- fp32 -> bf16 weight conversion into fragment order
        int task = (blk - 5120) * 4 + wave;   // 0..511
        int mtx = task >> 8, rem = task & 255;
        int t = rem >> 7, panel = (rem >> 3) & 15, kk = rem & 7;
        const float* S = (mtx ? aw : qw) + (size_t)t * 65536
                       + (size_t)(panel * 16 + (lane & 15)) * 256 + kk * 32 + (lane >> 4) * 8;
        float4 f0 = *(const float4*)S;
        float4 f1 = *(const float4*)(S + 4);
        u16x8 o;
        o[0] = f2b(f0.x); o[1] = f2b(f0.y); o[2] = f2b(f0.z); o[3] = f2b(f0.w);
        o[4] = f2b(f1.x); o[5] = f2b(f1.y); o[6] = f2b(f1.z); o[7] = f2b(f1.w);
        unsigned short* D = (mtx ? awb : qwb) + (size_t)t * 65536
                          + (((size_t)(panel * 8 + kk)) << 9) + (lane << 3);
        *(u16x8*)D = o;
    } else {
        // ---- fold relation matrices into K/V weights (fragment-order output)
        int fb = blk - 5248;          // 0..63
        int r = fb & 3, m = (fb >> 2) & 7, which = fb >> 5;
        int tsel = r & 1;
        const float* S  = (which ? relM : relA) + ((size_t)r * 8 + m) * 1024;
        const float* Bg = (which ? vw : kw) + (size_t)tsel * 65536 + (size_t)m * 32 * 256;
        const float* bv = (which ? vb : kb) + tsel * 256 + m * 32;
        unsigned short* Wf = (which ? wmsgb : wattb) + (size_t)r * 65536;
        float* bo = (which ? bmsg : batt) + r * 256 + m * 32;

        for (int i = threadIdx.x; i < 32 * 256; i += 256)
            Bl[i >> 8][i & 255] = Bg[(size_t)(i >> 8) * 256 + (i & 255)];
        __syncthreads();

        int a  = threadIdx.x >> 3;        // output row within 32 (j = m*32+a)
        int c0 = (threadIdx.x & 7) * 4;   // column phase; c = c0 + cc*32 + e
        float srow[32];
        #pragma unroll
        for (int bq = 0; bq < 32; ++bq)
            srow[bq] = which ? S[bq * 32 + a] : S[a * 32 + bq];
        float acc[8][4] = {{0.f}};
        #pragma unroll
        for (int bq = 0; bq < 32; ++bq) {
            float s = srow[bq];
            #pragma unroll
            for (int cc = 0; cc < 8; ++cc) {
                float4 bb = *(const float4*)&Bl[bq][c0 + cc * 32];
                acc[cc][0] += s * bb.x; acc[cc][1] += s * bb.y;
                acc[cc][2] += s * bb.z; acc[cc][3] += s * bb.w;
            }
        }
        int colpanel = m * 2 + (a >> 4);
        int jr = a & 15;
        #pragma unroll
        for (int cc = 0; cc < 8; ++cc) {
            ushort4 w4;
            w4.x = f2b(acc[cc][0]); w4.y = f2b(acc[cc][1]);
            w4.z = f2b(acc[cc][2]); w4.w = f2b(acc[cc][3]);
            *(ushort4*)(Wf + (((size_t)(colpanel * 8 + cc)) << 9)
                           + ((c0 >> 3) << 7) + (jr << 3) + (c0 & 7)) = w4;
        }
        if (threadIdx.x < 32) {
            int p = threadIdx.x;
            float s = 0.f;
            #pragma unroll
            for (int bq = 0; bq < 32; ++bq)
                s += (which ? S[bq * 32 + p] : S[p * 32 + bq]) * bv[bq];
            bo[p] = s;
        }
    }
}

// ---------------- Fused QKV-mod GEMM: grid (NTOK/64, 5). Frag-order inputs, coalesced loads.
__global__ __launch_bounds__(256) void gemm_qkv(const short* __restrict__ X,
        const short* __restrict__ qwb, const short* __restrict__ wattb,
        const short* __restrict__ wmsgb,
        const float* __restrict__ qb, const float* __restrict__ batt,
        const float* __restrict__ bmsg,
        const float* __restrict__ prior, unsigned short* __restrict__ OutBase) {
    int blkrow = blockIdx.x * 64;
    int s = blockIdx.y;
    int l = blkrow >> 12;
    int t = clamp01((int)prior[(size_t)l * HW * 3 + 2]);

    const short* Wp; const float* Bp;
    if (s == 0)      { Wp = qwb   + (size_t)t * 65536;                          Bp = qb   + t * 256; }
    else if (s <= 2) { int i2 = (s - 1) * 2 + t; Wp = wattb + (size_t)i2 * 65536; Bp = batt + i2 * 256; }
    else             { int i2 = (s - 3) * 2 + t; Wp = wmsgb + (size_t)i2 * 65536; Bp = bmsg + i2 * 256; }
    unsigned short* Out = OutBase + (size_t)s * NTOK * 256;

    int wave = threadIdx.x >> 6, lane = threadIdx.x & 63;
    int lr = lane & 15;
    const short* Xf = X + (((size_t)blockIdx.x * 4) << 12);  // 4 row-panels * 8 kk * 512

    f32x4 acc[4][4];
    #pragma unroll
    for (int mr = 0; mr < 4; ++mr)
        #pragma unroll
        for (int nr = 0; nr < 4; ++nr) acc[mr][nr] = (f32x4){0.f, 0.f, 0.f, 0.f};

    #pragma unroll
    for (int kk = 0; kk < 8; ++kk) {
        bf16x8 af[4], bf[4];
        #pragma unroll
        for (int mr = 0; mr < 4; ++mr)
            af[mr] = *(const bf16x8*)(Xf + (((size_t)(mr * 8 + kk)) << 9) + (lane << 3));
        #pragma unroll
        for (int nr = 0; nr < 4; ++nr)
            bf[nr] = *(const bf16x8*)(Wp + (((size_t)((wave * 4 + nr) * 8 + kk)) << 9) + (lane << 3));
        #pragma unroll
        for (int mr = 0; mr < 4; ++mr)
            #pragma unroll
            for (int nr = 0; nr < 4; ++nr)
                acc[mr][nr] = __builtin_amdgcn_mfma_f32_16x16x32_bf16(af[mr], bf[nr], acc[mr][nr], 0, 0, 0);
    }

    #pragma unroll
    for (int nr = 0; nr < 4; ++nr) {
        int col = wave * 64 + nr * 16 + lr;
        float bias = Bp[col];
        #pragma unroll
        for (int mr = 0; mr < 4; ++mr) {
            #pragma unroll
            for (int rr = 0; rr < 4; ++rr) {
                int row = blkrow + mr * 16 + (lane >> 4) * 4 + rr;
                Out[(size_t)row * 256 + col] = f2b(acc[mr][nr][rr] + bias);
            }
        }
    }
}

// ---------------- Output GEMM: attb(frag) @ awb(frag) + ab -> fp32 out (row-major).
__global__ __launch_bounds__(256) void gemm_a(const short* __restrict__ X,
        const short* __restrict__ W, const float* __restrict__ Bias,
        const float* __restrict__ prior, float* __restrict__ Out) {
    int blkrow = blockIdx.x * 64;
    int l = blkrow >> 12;
    int t = clamp01((int)prior[(size_t)l * HW * 3 + 2]);
    const short* Wp = W + (size_t)t * 65536;
    const float* Bp = Bias + (size_t)t * 256;

    int wave = threadIdx.x >> 6, lane = threadIdx.x & 63;
    int lr = lane & 15;
    const short* Xf = X + (((size_t)blockIdx.x * 4) << 12);

    f32x4 acc[4][4];
    #pragma unroll
    for (int mr = 0; mr < 4; ++mr)
        #pragma unroll
        for (int nr = 0; nr < 4; ++nr) acc[mr][nr] = (f32x4){0.f, 0.f, 0.f, 0.f};

    #pragma unroll
    for (int kk = 0; kk < 8; ++kk) {
        bf16x8 af[4], bf[4];
        #pragma unroll
        for (int mr = 0; mr < 4; ++mr)
            af[mr] = *(const bf16x8*)(Xf + (((size_t)(mr * 8 + kk)) << 9) + (lane << 3));
        #pragma unroll
        for (int nr = 0; nr < 4; ++nr)
            bf[nr] = *(const bf16x8*)(Wp + (((size_t)((wave * 4 + nr) * 8 + kk)) << 9) + (lane << 3));
        #pragma unroll
        for (int mr = 0; mr < 4; ++mr)
            #pragma unroll
            for (int nr = 0; nr < 4; ++nr)
                acc[mr][nr] = __builtin_amdgcn_mfma_f32_16x16x32_bf16(af[mr], bf[nr], acc[mr][nr], 0, 0, 0);
    }

    #pragma unroll
    for (int nr = 0; nr < 4; ++nr) {
        int col = wave * 64 + nr * 16 + lr;
        float bias = Bp[col];
        #pragma unroll
        for (int mr = 0; mr < 4; ++mr) {
            #pragma unroll
            for (int rr = 0; rr < 4; ++rr) {
                int row = blkrow + mr * 16 + (lane >> 4) * 4 + rr;
                Out[(size_t)row * 256 + col] = acc[mr][nr][rr] + bias;
            }
        }
    }
}

// ---------------- Final attention: writes attb in fragment order for gemm_a
__global__ __launch_bounds__(256) void attn_final(
        const unsigned short* __restrict__ Q, const unsigned short* __restrict__ Km,
        const unsigned short* __restrict__ Vm,
        const int* __restrict__ mask, const float* __restrict__ prior,
        unsigned short* __restrict__ attb) {
    const size_t TSTR = (size_t)NTOK * 256;
    int m = blockIdx.y;
    int wave = threadIdx.x >> 6, lane = threadIdx.x & 63;
    int col = lane & 31, half = lane >> 5;
    int hw = blockIdx.x * 8 + wave * 2 + half;

    int t_[LL], msk[LL];
    #pragma unroll
    for (int i = 0; i < LL; ++i) t_[i] = clamp01((int)prior[(size_t)i * HW * 3 + 2]);
    #pragma unroll
    for (int j = 0; j < LL; ++j) msk[j] = mask[hw * LL + j];

    float q[LL], km0[LL], km1[LL], vm0[LL], vm1[LL];
    #pragma unroll
    for (int j = 0; j < LL; ++j) {
        size_t idx = (size_t)(j * HW + hw) * 256 + m * 32 + col;
        q[j]   = b2f(Q[idx]);
        km0[j] = b2f(Km[idx]);
        km1[j] = b2f(Km[TSTR + idx]);
        vm0[j] = b2f(Vm[idx]);
        vm1[j] = b2f(Vm[TSTR + idx]);
    }

    const float scale = 0.17677669529663687f;  // 1/sqrt(32)
    #pragma unroll
    for (int i = 0; i < LL; ++i) {
        int sel = t_[i];
        float s[LL];
        #pragma unroll
        for (int j = 0; j < LL; ++j) {
            float pr = q[i] * (sel ? km1[j] : km0[j]);
            #pragma unroll
            for (int off = 16; off; off >>= 1) pr += __shfl_xor(pr, off);
            s[j] = msk[j] ? pr * scale : -1e9f;
        }
        float mx = fmaxf(fmaxf(fmaxf(s[0], s[1]), fmaxf(s[2], s[3])), s[4]);
        float e[LL], sum = 0.f;
        #pragma unroll
        for (int j = 0; j < LL; ++j) { e[j] = __expf(s[j] - mx); sum += e[j]; }
        float inv = 1.f / sum;
        float o = 0.f;
        #pragma unroll
        for (int j = 0; j < LL; ++j) o += e[j] * (sel ? vm1[j] : vm0[j]);
        o *= inv;
        // fragment-order write: row = i*HW+hw, c = m*32+col
        size_t off = (((size_t)(i * 256 + (hw >> 4)) * 8 + m) << 9)
                   + ((col >> 3) << 7) + ((hw & 15) << 3) + (col & 7);
        attb[off] = f2b(o);
    }
}

extern "C" void kernel_launch(void* const* d_in, const int* in_sizes, int n_in,
                              void* d_out, int out_size, void* d_ws, size_t ws_size,
                              hipStream_t stream) {
    (void)in_sizes; (void)n_in; (void)out_size; (void)ws_size;
    const float* x     = (const float*)d_in[0];
    const int*   mask  = (const int*)d_in[1];
    const float* prior = (const float*)d_in[2];
    const float* ln_g  = (const float*)d_in[3];
    const float* ln_b  = (const float*)d_in[4];
    const float* qw    = (const float*)d_in[5];
    const float* qb    = (const float*)d_in[6];
    const float* kw    = (const float*)d_in[7];
    const float* kb    = (const float*)d_in[8];
    const float* vw    = (const float*)d_in[9];
    const float* vb    = (const float*)d_in[10];
    const float* aw    = (const float*)d_in[11];
    const float* ab    = (const float*)d_in[12];
    const float* relA  = (const float*)d_in[13];
    const float* relM  = (const float*)d_in[14];
    float* out = (float*)d_out;

    char* ws = (char*)d_ws;
    const size_t TOKB = (size_t)NTOK * 256 * 2;  // bf16 token buffer bytes
    unsigned short* xnb  = (unsigned short*)(ws);
    unsigned short* Qb   = (unsigned short*)(ws + TOKB);       // Q, Km0, Km1, Vm0, Vm1 contiguous
    unsigned short* Kmb  = (unsigned short*)(ws + 2 * TOKB);
    unsigned short* Vmb  = (unsigned short*)(ws + 4 * TOKB);
    unsigned short* attb = (unsigned short*)(ws + 6 * TOKB);
    char* wsp = ws + 7 * TOKB;
    unsigned short* qwb   = (unsigned short*)(wsp);            wsp += 131072 * 2;
    unsigned short* awb   = (unsigned short*)(wsp);            wsp += 131072 * 2;
    unsigned short* wattb = (unsigned short*)(wsp);            wsp += 4 * 65536 * 2;
    unsigned short* wmsgb = (unsigned short*)(wsp);            wsp += 4 * 65536 * 2;
    float* batt = (float*)(wsp);                               wsp += 4 * 256 * 4;
    float* bmsg = (float*)(wsp);

    setup_kernel<<<5312, 256, 0, stream>>>(x, ln_g, ln_b, xnb, qw, aw, qwb, awb,
                                           relA, relM, kw, vw, kb, vb,
                                           wattb, wmsgb, batt, bmsg);

    gemm_qkv<<<dim3(NTOK / 64, 5), 256, 0, stream>>>((const short*)xnb,
            (const short*)qwb, (const short*)wattb, (const short*)wmsgb,
            qb, batt, bmsg, prior, Qb);

    attn_final<<<dim3(HW / 8, HEADS), 256, 0, stream>>>(Qb, Kmb, Vmb, mask, prior, attb);

    gemm_a<<<NTOK / 64, 256, 0, stream>>>((const short*)attb, (const short*)awb, ab, prior, out);
}